// Round 8
// baseline (299.599 us; speedup 1.0000x reference)
//
#include <hip/hip_runtime.h>
#include <hip/hip_bf16.h>
#include <math.h>

#define DIMC 1024
#define NHEADS 16
#define HDIM 64
#define BATCH 4
#define SEQ 2048
#define NROWS (BATCH * SEQ)      // 8192
#define ATTN_SCALE 0.125f        // 64^-0.5
#define LOG2E 1.4426950408889634f

typedef __attribute__((ext_vector_type(8))) short short8;   // 8 bf16 = 4 VGPR
typedef __attribute__((ext_vector_type(4))) short short4v;  // 4 bf16 = 2 VGPR
typedef __attribute__((ext_vector_type(4))) float f32x4;    // MFMA C/D

static __device__ __forceinline__ short f2bf(float f) {
    __hip_bfloat16 h = __float2bfloat16(f);
    return *reinterpret_cast<short*>(&h);
}

// async global->LDS, 16B per lane; LDS dest = wave-uniform base + lane*16
static __device__ __forceinline__ void gload16(const void* g, void* l) {
    __builtin_amdgcn_global_load_lds(
        (const __attribute__((address_space(1))) unsigned int*)g,
        (__attribute__((address_space(3))) unsigned int*)l, 16, 0, 0);
}

// ---------------------------------------------------------------------------
// X fp32 -> bf16 (row-major copy), 8 elems/thread
// ---------------------------------------------------------------------------
__global__ __launch_bounds__(256)
void xcvt(const float* __restrict__ in, unsigned short* __restrict__ out) {
    int i = blockIdx.x * 256 + threadIdx.x;
    const float4* p = reinterpret_cast<const float4*>(in) + 2 * i;
    float4 a = p[0], b = p[1];
    short8 pk;
    pk[0] = f2bf(a.x); pk[1] = f2bf(a.y); pk[2] = f2bf(a.z); pk[3] = f2bf(a.w);
    pk[4] = f2bf(b.x); pk[5] = f2bf(b.y); pk[6] = f2bf(b.z); pk[7] = f2bf(b.w);
    reinterpret_cast<short8*>(out)[i] = pk;
}

// ---------------------------------------------------------------------------
// transpose + fp32->bf16: src fp32 [1024][N] -> dst bf16 [N][1024]
// ---------------------------------------------------------------------------
__global__ __launch_bounds__(256)
void transpose_cvt(const float* __restrict__ src, unsigned short* __restrict__ dst,
                   int N) {
    __shared__ float t[64][65];
    const int tid = threadIdx.x;
    const int cb = blockIdx.x * 64;
    const int rb = blockIdx.y * 64;
#pragma unroll
    for (int e = 0; e < 4; e++) {
        int idx = tid + e * 256;
        int row = idx >> 4;
        int c4 = (idx & 15) << 2;
        *reinterpret_cast<float4*>(&t[row][c4]) =
            *reinterpret_cast<const float4*>(&src[(size_t)(rb + row) * N + cb + c4]);
    }
    __syncthreads();
#pragma unroll
    for (int e = 0; e < 2; e++) {
        int idx = tid + e * 256;
        int col = idx >> 3;
        int k8 = (idx & 7) << 3;
        short8 pk;
#pragma unroll
        for (int j = 0; j < 8; j++) pk[j] = f2bf(t[k8 + j][col]);
        *reinterpret_cast<short8*>(&dst[(size_t)(cb + col) * 1024 + rb + k8]) = pk;
    }
}

// ---------------------------------------------------------------------------
// qkv: Xbf bf16 [8192][1024] x Wt bf16 [3072][1024] -> bf16 q,k [B,H,S,D], vt [B,H,D,S]
// global_load_lds staging (m97 structure), LDS linear [128][32]
// ---------------------------------------------------------------------------
__global__ __launch_bounds__(256)
void qkv_gemm_mfma(const unsigned short* __restrict__ Xbf,
                   const unsigned short* __restrict__ Wt,
                   unsigned short* __restrict__ qo, unsigned short* __restrict__ ko,
                   unsigned short* __restrict__ vt) {
    __shared__ short Alds[128][32];
    __shared__ short Blds[128][32];
    const int tid = threadIdx.x;
    const int lane = tid & 63;
    const int wave = tid >> 6;
    const int wr = wave >> 1, wc = wave & 1;
    const int rowbase = blockIdx.y * 128;
    const int colbase = blockIdx.x * 128;
    const int g = lane >> 4, li = lane & 15;
    const int srow0 = (wave * 2 + 0) * 16 + (lane >> 2);
    const int srow1 = (wave * 2 + 1) * 16 + (lane >> 2);
    const int scol = (lane & 3) * 8;
    short* aflat = &Alds[0][0];
    short* bflat = &Blds[0][0];

    f32x4 acc[4][4];
#pragma unroll
    for (int m = 0; m < 4; m++)
#pragma unroll
        for (int n = 0; n < 4; n++) acc[m][n] = (f32x4){0.f, 0.f, 0.f, 0.f};

    for (int k0 = 0; k0 < DIMC; k0 += 32) {
        gload16(&Xbf[(size_t)(rowbase + srow0) * DIMC + k0 + scol],
                aflat + (wave * 2 + 0) * 512);
        gload16(&Xbf[(size_t)(rowbase + srow1) * DIMC + k0 + scol],
                aflat + (wave * 2 + 1) * 512);
        gload16(&Wt[(size_t)(colbase + srow0) * 1024 + k0 + scol],
                bflat + (wave * 2 + 0) * 512);
        gload16(&Wt[(size_t)(colbase + srow1) * 1024 + k0 + scol],
                bflat + (wave * 2 + 1) * 512);
        __syncthreads();
        short8 af[4], bfr[4];
#pragma unroll
        for (int m = 0; m < 4; m++)
            af[m] = *reinterpret_cast<const short8*>(&Alds[wr * 64 + m * 16 + li][g * 8]);
#pragma unroll
        for (int n = 0; n < 4; n++)
            bfr[n] = *reinterpret_cast<const short8*>(&Blds[wc * 64 + n * 16 + li][g * 8]);
#pragma unroll
        for (int m = 0; m < 4; m++)
#pragma unroll
            for (int n = 0; n < 4; n++)
                acc[m][n] = __builtin_amdgcn_mfma_f32_16x16x32_bf16(
                    af[m], bfr[n], acc[m][n], 0, 0, 0);
        __syncthreads();
    }

    const int col0 = colbase + wc * 64;
    const int three = col0 >> 10;
    const int h = (col0 & 1023) >> 6;
    if (three < 2) {
        unsigned short* dst = (three == 0) ? qo : ko;
        const float mult = (three == 0) ? (ATTN_SCALE * LOG2E) : 1.0f;
#pragma unroll
        for (int n = 0; n < 4; n++) {
            int d = n * 16 + li;
#pragma unroll
            for (int m = 0; m < 4; m++) {
                int r0 = rowbase + wr * 64 + m * 16 + g * 4;
                int b = r0 >> 11;
                size_t base = ((size_t)(b * NHEADS + h) * SEQ) * HDIM + d;
#pragma unroll
                for (int r = 0; r < 4; r++) {
                    int s = (r0 + r) & 2047;
                    dst[base + (size_t)s * HDIM] = (unsigned short)f2bf(acc[m][n][r] * mult);
                }
            }
        }
    } else {
#pragma unroll
        for (int n = 0; n < 4; n++) {
            int d = n * 16 + li;
#pragma unroll
            for (int m = 0; m < 4; m++) {
                int r0 = rowbase + wr * 64 + m * 16 + g * 4;
                int b = r0 >> 11, s0 = r0 & 2047;
                short4v pk;
#pragma unroll
                for (int r = 0; r < 4; r++) pk[r] = f2bf(acc[m][n][r]);
                *reinterpret_cast<short4v*>(
                    &vt[((size_t)(b * NHEADS + h) * HDIM + d) * SEQ + s0]) = pk;
            }
        }
    }
}

// ---------------------------------------------------------------------------
// proj: Abf bf16 [8192][1024] x Wt bf16 [1024][1024] + bias -> out fp32
// ---------------------------------------------------------------------------
__global__ __launch_bounds__(256)
void proj_gemm_mfma(const unsigned short* __restrict__ Abf,
                    const unsigned short* __restrict__ Wt,
                    const float* __restrict__ bias, float* __restrict__ out) {
    __shared__ short Alds[128][32];
    __shared__ short Blds[128][32];
    const int tid = threadIdx.x;
    const int lane = tid & 63;
    const int wave = tid >> 6;
    const int wr = wave >> 1, wc = wave & 1;
    const int rowbase = blockIdx.y * 128;
    const int colbase = blockIdx.x * 128;
    const int g = lane >> 4, li = lane & 15;
    const int srow0 = (wave * 2 + 0) * 16 + (lane >> 2);
    const int srow1 = (wave * 2 + 1) * 16 + (lane >> 2);
    const int scol = (lane & 3) * 8;
    short* aflat = &Alds[0][0];
    short* bflat = &Blds[0][0];

    f32x4 acc[4][4];
#pragma unroll
    for (int m = 0; m < 4; m++)
#pragma unroll
        for (int n = 0; n < 4; n++) acc[m][n] = (f32x4){0.f, 0.f, 0.f, 0.f};

    for (int k0 = 0; k0 < DIMC; k0 += 32) {
        gload16(&Abf[(size_t)(rowbase + srow0) * DIMC + k0 + scol],
                aflat + (wave * 2 + 0) * 512);
        gload16(&Abf[(size_t)(rowbase + srow1) * DIMC + k0 + scol],
                aflat + (wave * 2 + 1) * 512);
        gload16(&Wt[(size_t)(colbase + srow0) * 1024 + k0 + scol],
                bflat + (wave * 2 + 0) * 512);
        gload16(&Wt[(size_t)(colbase + srow1) * 1024 + k0 + scol],
                bflat + (wave * 2 + 1) * 512);
        __syncthreads();
        short8 af[4], bfr[4];
#pragma unroll
        for (int m = 0; m < 4; m++)
            af[m] = *reinterpret_cast<const short8*>(&Alds[wr * 64 + m * 16 + li][g * 8]);
#pragma unroll
        for (int n = 0; n < 4; n++)
            bfr[n] = *reinterpret_cast<const short8*>(&Blds[wc * 64 + n * 16 + li][g * 8]);
#pragma unroll
        for (int m = 0; m < 4; m++)
#pragma unroll
            for (int n = 0; n < 4; n++)
                acc[m][n] = __builtin_amdgcn_mfma_f32_16x16x32_bf16(
                    af[m], bfr[n], acc[m][n], 0, 0, 0);
        __syncthreads();
    }

#pragma unroll
    for (int n = 0; n < 4; n++) {
        int col = colbase + wc * 64 + n * 16 + li;
        float bv = bias[col];
#pragma unroll
        for (int m = 0; m < 4; m++) {
            int r0 = rowbase + wr * 64 + m * 16 + g * 4;
#pragma unroll
            for (int r = 0; r < 4; r++)
                out[(size_t)(r0 + r) * DIMC + col] = acc[m][n][r] + bv;
        }
    }
}

// ---------------------------------------------------------------------------
// MFMA flash attention (causal), exp2-domain softmax.
//  - 1024 blocks: one 128-row q-tile each; XCD-chunked (8 heads/XCD) with
//    longest-qtile-first order inside each chunk (work ~ qtile)
//  - tree reductions (depth 4), truncation bf16 pack for P
//  - coalesced K/V staging, double-buffered, pointer-increment addressing
// ---------------------------------------------------------------------------
__global__ __launch_bounds__(256)
void flash_attn_mfma(const unsigned short* __restrict__ qg,
                     const unsigned short* __restrict__ kg,
                     const unsigned short* __restrict__ vt,
                     unsigned short* __restrict__ og) {
    __shared__ short Klds[2][64][64];
    __shared__ short Vlds[2][64][64];
    __shared__ short Plds[4][32][64];
    const int tid = threadIdx.x;
    const int lane = tid & 63;
    const int w = tid >> 6;
    const int g = lane >> 4, li = lane & 15;
    const int sw = li & 7;
    // 1024 blocks; XCD chunk = 128 consecutive swz ids (8 heads x 16 qtiles);
    // within a chunk: head-major, qtile DESCENDING (long blocks dispatch first)
    const int orig = blockIdx.x;                   // 0..1023
    const int swz = (orig & 7) * 128 + (orig >> 3);
    const int bh = swz >> 4;                       // head 0..63
    const int qtile = 15 - (swz & 15);             // 15..0
    const size_t head = (size_t)bh * SEQ * HDIM;
    const int b = bh >> 4, h = bh & 15;

    const int c0r = tid >> 3, c0c = tid & 7;       // c1: +32 rows, same col

    const int qbase = qtile * 128;
    const int qw = qbase + w * 32;
    const int nt = 2 * qtile + 2;

    // Q fragments: col q=li+16n, k d=32*ds+8g+j
    short8 bq[2][2];
#pragma unroll
    for (int n = 0; n < 2; n++)
#pragma unroll
        for (int ds = 0; ds < 2; ds++)
            bq[n][ds] = *reinterpret_cast<const short8*>(
                &qg[head + (size_t)(qw + li + 16 * n) * HDIM + ds * 32 + g * 8]);

    f32x4 accO[4][2];
#pragma unroll
    for (int df = 0; df < 4; df++)
#pragma unroll
        for (int n = 0; n < 2; n++) accO[df][n] = (f32x4){0.f, 0.f, 0.f, 0.f};
    float mrow[2] = {-INFINITY, -INFINITY};
    float lrow[2] = {0.f, 0.f};

    // staging pointers (advance by constants per tile)
    const unsigned short* kp = kg + head + (size_t)c0r * HDIM + c0c * 8;
    const unsigned short* vp = vt + head + (size_t)c0r * SEQ + c0c * 8;

    short8 kreg0, kreg1, vreg0, vreg1;
    kreg0 = *reinterpret_cast<const short8*>(kp);
    kreg1 = *reinterpret_cast<const short8*>(kp + 32 * HDIM);
    vreg0 = *reinterpret_cast<const short8*>(vp);
    vreg1 = *reinterpret_cast<const short8*>(vp + 32 * SEQ);
    kp += 64 * HDIM; vp += 64;
    {
        const int sw0 = (c0c ^ (c0r & 7)) * 8;
        const int sw1 = (c0c ^ ((c0r + 32) & 7)) * 8;
        *reinterpret_cast<short8*>(&Klds[0][c0r][sw0]) = kreg0;
        *reinterpret_cast<short8*>(&Vlds[0][c0r][sw0]) = vreg0;
        *reinterpret_cast<short8*>(&Klds[0][c0r + 32][sw1]) = kreg1;
        *reinterpret_cast<short8*>(&Vlds[0][c0r + 32][sw1]) = vreg1;
    }
    __syncthreads();

    for (int t = 0; t < nt; t++) {
        const int kvbase = t * 64;
        const int buf = t & 1;
        const bool more = (t + 1 < nt);
        if (more) {      // issue next-tile loads NOW; latency hides under compute
            kreg0 = *reinterpret_cast<const short8*>(kp);
            kreg1 = *reinterpret_cast<const short8*>(kp + 32 * HDIM);
            vreg0 = *reinterpret_cast<const short8*>(vp);
            vreg1 = *reinterpret_cast<const short8*>(vp + 32 * SEQ);
            kp += 64 * HDIM; vp += 64;
        }

        if (kvbase <= qw + 31) {
            // ---- S^T = K·Q^T ----
            f32x4 s[4][2];
#pragma unroll
            for (int m = 0; m < 4; m++)
#pragma unroll
                for (int n = 0; n < 2; n++) s[m][n] = (f32x4){0.f, 0.f, 0.f, 0.f};
#pragma unroll
            for (int ds = 0; ds < 2; ds++) {
                short8 ak[4];
#pragma unroll
                for (int m = 0; m < 4; m++)
                    ak[m] = *reinterpret_cast<const short8*>(
                        &Klds[buf][li + 16 * m][(((ds * 4 + g) ^ sw)) * 8]);
#pragma unroll
                for (int m = 0; m < 4; m++)
#pragma unroll
                    for (int n = 0; n < 2; n++)
                        s[m][n] = __builtin_amdgcn_mfma_f32_16x16x32_bf16(
                            ak[m], bq[n][ds], s[m][n], 0, 0, 0);
            }
            // ---- mask (diag tiles only) ----
            const bool diag = (kvbase + 63 > qw);
            if (diag) {
#pragma unroll
                for (int n = 0; n < 2; n++) {
                    int q = qw + li + 16 * n;
#pragma unroll
                    for (int m = 0; m < 4; m++)
#pragma unroll
                        for (int r = 0; r < 4; r++) {
                            int kv = kvbase + 16 * m + 4 * g + r;
                            if (kv > q) s[m][n][r] = -INFINITY;
                        }
                }
            }
            // ---- tile max (tree, depth 4) + corr ----
            float corr[2];
#pragma unroll
            for (int n = 0; n < 2; n++) {
                float a0 = fmaxf(fmaxf(s[0][n][0], s[0][n][1]), fmaxf(s[0][n][2], s[0][n][3]));
                float a1 = fmaxf(fmaxf(s[1][n][0], s[1][n][1]), fmaxf(s[1][n][2], s[1][n][3]));
                float a2 = fmaxf(fmaxf(s[2][n][0], s[2][n][1]), fmaxf(s[2][n][2], s[2][n][3]));
                float a3 = fmaxf(fmaxf(s[3][n][0], s[3][n][1]), fmaxf(s[3][n][2], s[3][n][3]));
                float tm = fmaxf(fmaxf(a0, a1), fmaxf(a2, a3));
                tm = fmaxf(tm, __shfl_xor(tm, 16));
                tm = fmaxf(tm, __shfl_xor(tm, 32));
                float mnew = fmaxf(mrow[n], tm);
                corr[n] = __builtin_amdgcn_exp2f(mrow[n] - mnew);
                mrow[n] = mnew;
            }
            // ---- P = exp2(S-m), truncation pack to LDS, partial sums ----
            float sm[4][2];
#pragma unroll
            for (int m = 0; m < 4; m++) {
#pragma unroll
                for (int n = 0; n < 2; n++) {
                    float p0 = __builtin_amdgcn_exp2f(s[m][n][0] - mrow[n]);
                    float p1 = __builtin_amdgcn_exp2f(s[m][n][1] - mrow[n]);
                    float p2 = __builtin_amdgcn_exp2f(s[m][n][2] - mrow[n]);
                    float p3 = __builtin_amdgcn_exp2f(s[m][n][3] - mrow[n]);
                    sm[m][n] = (p0 + p1) + (p2 + p3);
                    // truncation bf16 pack: [p0,p1] and [p2,p3]
                    unsigned u01 = (__float_as_uint(p1) & 0xFFFF0000u) |
                                   (__float_as_uint(p0) >> 16);
                    unsigned u23 = (__float_as_uint(p3) & 0xFFFF0000u) |
                                   (__float_as_uint(p2) >> 16);
                    *reinterpret_cast<uint2*>(
                        &Plds[w][li + 16 * n]
                             [((2 * m + (g >> 1)) ^ sw) * 8 + (g & 1) * 4]) =
                        make_uint2(u01, u23);
                }
            }
#pragma unroll
            for (int n = 0; n < 2; n++) {
                float ts = (sm[0][n] + sm[1][n]) + (sm[2][n] + sm[3][n]);
                ts += __shfl_xor(ts, 16);
                ts += __shfl_xor(ts, 32);
                lrow[n] = lrow[n] * corr[n] + ts;
            }
            // ---- O rescale (skipped when max unchanged across wave) ----
            bool nore = (corr[0] == 1.0f) && (corr[1] == 1.0f);
            if (!__all((int)nore)) {
#pragma unroll
                for (int df = 0; df < 4; df++)
#pragma unroll
                    for (int n = 0; n < 2; n++) {
                        accO[df][n][0] *= corr[n]; accO[df][n][1] *= corr[n];
                        accO[df][n][2] *= corr[n]; accO[df][n][3] *= corr[n];
                    }
            }
            // ---- O^T += V^T·P^T ----
#pragma unroll
            for (int ks = 0; ks < 2; ks++) {
                short8 av[4], bp[2];
#pragma unroll
                for (int df = 0; df < 4; df++)
                    av[df] = *reinterpret_cast<const short8*>(
                        &Vlds[buf][li + 16 * df][((ks * 4 + g) ^ sw) * 8]);
#pragma unroll
                for (int n = 0; n < 2; n++)
                    bp[n] = *reinterpret_cast<const short8*>(
                        &Plds[w][li + 16 * n][((ks * 4 + g) ^ sw) * 8]);
#pragma unroll
                for (int df = 0; df < 4; df++)
#pragma unroll
                    for (int n = 0; n < 2; n++)
                        accO[df][n] = __builtin_amdgcn_mfma_f32_16x16x32_bf16(
                            av[df], bp[n], accO[df][n], 0, 0, 0);
            }
        }

        if (more) {
            const int nbuf = buf ^ 1;
            const int sw0 = (c0c ^ (c0r & 7)) * 8;
            const int sw1 = (c0c ^ ((c0r + 32) & 7)) * 8;
            *reinterpret_cast<short8*>(&Klds[nbuf][c0r][sw0]) = kreg0;
            *reinterpret_cast<short8*>(&Vlds[nbuf][c0r][sw0]) = vreg0;
            *reinterpret_cast<short8*>(&Klds[nbuf][c0r + 32][sw1]) = kreg1;
            *reinterpret_cast<short8*>(&Vlds[nbuf][c0r + 32][sw1]) = vreg1;
        }
        __syncthreads();
    }

    // epilogue: O[q][d] = accO^T / l
#pragma unroll
    for (int n = 0; n < 2; n++) {
        float inv = 1.0f / lrow[n];
        int q = qw + li + 16 * n;
        size_t rowoff = (size_t)(b * SEQ + q) * DIMC + h * HDIM;
#pragma unroll
        for (int df = 0; df < 4; df++) {
            short4v pk;
#pragma unroll
            for (int r = 0; r < 4; r++) pk[r] = f2bf(accO[df][n][r] * inv);
            *reinterpret_cast<short4v*>(&og[rowoff + 16 * df + 4 * g]) = pk;
        }
    }
}

extern "C" void kernel_launch(void* const* d_in, const int* in_sizes, int n_in,
                              void* d_out, int out_size, void* d_ws, size_t ws_size,
                              hipStream_t stream) {
    const float* x      = (const float*)d_in[0];   // [4,2048,1024]
    const float* w_qkv  = (const float*)d_in[1];   // [1024,3072]
    const float* w_proj = (const float*)d_in[2];   // [1024,1024]
    const float* b_proj = (const float*)d_in[3];   // [1024]
    float* out = (float*)d_out;                    // [4,2048,1024] fp32

    char* w = (char*)d_ws;
    unsigned short* qb  = (unsigned short*)(w);                        // 16 MB
    unsigned short* kb  = (unsigned short*)(w + ((size_t)16 << 20));   // 16 MB
    unsigned short* vtb = (unsigned short*)(w + ((size_t)32 << 20));   // 16 MB [B,H,D,S]
    unsigned short* ao  = (unsigned short*)(w + ((size_t)48 << 20));   // 16 MB
    unsigned short* wqt = (unsigned short*)(w + ((size_t)64 << 20));   // 6 MB
    unsigned short* wpt = (unsigned short*)(w + ((size_t)72 << 20));   // 2 MB
    unsigned short* xbf = (unsigned short*)(w + ((size_t)80 << 20));   // 16 MB

    xcvt<<<NROWS * DIMC / (256 * 8), 256, 0, stream>>>(x, xbf);
    transpose_cvt<<<dim3(3 * DIMC / 64, DIMC / 64), 256, 0, stream>>>(w_qkv, wqt, 3 * DIMC);
    transpose_cvt<<<dim3(DIMC / 64, DIMC / 64), 256, 0, stream>>>(w_proj, wpt, DIMC);
    qkv_gemm_mfma<<<dim3(3 * DIMC / 128, NROWS / 128), 256, 0, stream>>>(xbf, wqt, qb, kb, vtb);
    flash_attn_mfma<<<1024, 256, 0, stream>>>(qb, kb, vtb, ao);
    proj_gemm_mfma<<<dim3(DIMC / 128, NROWS / 128), 256, 0, stream>>>(ao, wpt, b_proj, out);
}

// Round 9
// 279.699 us; speedup vs baseline: 1.0711x; 1.0711x over previous
//
#include <hip/hip_runtime.h>
#include <hip/hip_bf16.h>
#include <math.h>

#define DIMC 1024
#define NHEADS 16
#define HDIM 64
#define BATCH 4
#define SEQ 2048
#define NROWS (BATCH * SEQ)      // 8192
#define ATTN_SCALE 0.125f        // 64^-0.5
#define LOG2E 1.4426950408889634f

typedef __attribute__((ext_vector_type(8))) short short8;   // 8 bf16 = 4 VGPR
typedef __attribute__((ext_vector_type(4))) short short4v;  // 4 bf16 = 2 VGPR
typedef __attribute__((ext_vector_type(4))) float f32x4;    // MFMA C/D

static __device__ __forceinline__ short f2bf(float f) {
    __hip_bfloat16 h = __float2bfloat16(f);
    return *reinterpret_cast<short*>(&h);
}

// async global->LDS, 16B per lane; LDS dest = wave-uniform base + lane*16
static __device__ __forceinline__ void gload16(const void* g, void* l) {
    __builtin_amdgcn_global_load_lds(
        (const __attribute__((address_space(1))) unsigned int*)g,
        (__attribute__((address_space(3))) unsigned int*)l, 16, 0, 0);
}

// ---------------------------------------------------------------------------
// X fp32 -> bf16 (row-major copy), 8 elems/thread
// ---------------------------------------------------------------------------
__global__ __launch_bounds__(256)
void xcvt(const float* __restrict__ in, unsigned short* __restrict__ out) {
    int i = blockIdx.x * 256 + threadIdx.x;
    const float4* p = reinterpret_cast<const float4*>(in) + 2 * i;
    float4 a = p[0], b = p[1];
    short8 pk;
    pk[0] = f2bf(a.x); pk[1] = f2bf(a.y); pk[2] = f2bf(a.z); pk[3] = f2bf(a.w);
    pk[4] = f2bf(b.x); pk[5] = f2bf(b.y); pk[6] = f2bf(b.z); pk[7] = f2bf(b.w);
    reinterpret_cast<short8*>(out)[i] = pk;
}

// ---------------------------------------------------------------------------
// transpose + fp32->bf16: src fp32 [1024][N] -> dst bf16 [N][1024]
// ---------------------------------------------------------------------------
__global__ __launch_bounds__(256)
void transpose_cvt(const float* __restrict__ src, unsigned short* __restrict__ dst,
                   int N) {
    __shared__ float t[64][65];
    const int tid = threadIdx.x;
    const int cb = blockIdx.x * 64;
    const int rb = blockIdx.y * 64;
#pragma unroll
    for (int e = 0; e < 4; e++) {
        int idx = tid + e * 256;
        int row = idx >> 4;
        int c4 = (idx & 15) << 2;
        *reinterpret_cast<float4*>(&t[row][c4]) =
            *reinterpret_cast<const float4*>(&src[(size_t)(rb + row) * N + cb + c4]);
    }
    __syncthreads();
#pragma unroll
    for (int e = 0; e < 2; e++) {
        int idx = tid + e * 256;
        int col = idx >> 3;
        int k8 = (idx & 7) << 3;
        short8 pk;
#pragma unroll
        for (int j = 0; j < 8; j++) pk[j] = f2bf(t[k8 + j][col]);
        *reinterpret_cast<short8*>(&dst[(size_t)(cb + col) * 1024 + rb + k8]) = pk;
    }
}

// ---------------------------------------------------------------------------
// qkv: Xbf bf16 [8192][1024] x Wt bf16 [3072][1024] -> bf16 q,k [B,H,S,D], vt [B,H,D,S]
// m97 structure: BK=64, single-buffered global_load_lds, LDS linear [128][64]
// ---------------------------------------------------------------------------
__global__ __launch_bounds__(256)
void qkv_gemm_mfma(const unsigned short* __restrict__ Xbf,
                   const unsigned short* __restrict__ Wt,
                   unsigned short* __restrict__ qo, unsigned short* __restrict__ ko,
                   unsigned short* __restrict__ vt) {
    __shared__ short Alds[128][64];   // 16 KB
    __shared__ short Blds[128][64];   // 16 KB
    const int tid = threadIdx.x;
    const int lane = tid & 63;
    const int wave = tid >> 6;
    const int wr = wave >> 1, wc = wave & 1;
    const int rowbase = blockIdx.y * 128;
    const int colbase = blockIdx.x * 128;
    const int g = lane >> 4, li = lane & 15;
    const int sr = lane >> 3;          // 0..7 (row within 8-row chunk)
    const int sc = (lane & 7) * 8;     // k-col in shorts
    short* aflat = &Alds[0][0];
    short* bflat = &Blds[0][0];

    f32x4 acc[4][4];
#pragma unroll
    for (int m = 0; m < 4; m++)
#pragma unroll
        for (int n = 0; n < 4; n++) acc[m][n] = (f32x4){0.f, 0.f, 0.f, 0.f};

    for (int k0 = 0; k0 < DIMC; k0 += 64) {
#pragma unroll
        for (int e = 0; e < 4; e++) {
            int j = wave * 4 + e;      // 0..15: 8-row chunk index
            gload16(&Xbf[(size_t)(rowbase + j * 8 + sr) * DIMC + k0 + sc],
                    aflat + j * 512);
            gload16(&Wt[(size_t)(colbase + j * 8 + sr) * 1024 + k0 + sc],
                    bflat + j * 512);
        }
        __syncthreads();
#pragma unroll
        for (int ks = 0; ks < 2; ks++) {
            short8 af[4], bfr[4];
#pragma unroll
            for (int m = 0; m < 4; m++)
                af[m] = *reinterpret_cast<const short8*>(
                    &Alds[wr * 64 + m * 16 + li][ks * 32 + g * 8]);
#pragma unroll
            for (int n = 0; n < 4; n++)
                bfr[n] = *reinterpret_cast<const short8*>(
                    &Blds[wc * 64 + n * 16 + li][ks * 32 + g * 8]);
#pragma unroll
            for (int m = 0; m < 4; m++)
#pragma unroll
                for (int n = 0; n < 4; n++)
                    acc[m][n] = __builtin_amdgcn_mfma_f32_16x16x32_bf16(
                        af[m], bfr[n], acc[m][n], 0, 0, 0);
        }
        __syncthreads();
    }

    const int col0 = colbase + wc * 64;
    const int three = col0 >> 10;
    const int h = (col0 & 1023) >> 6;
    if (three < 2) {
        unsigned short* dst = (three == 0) ? qo : ko;
        const float mult = (three == 0) ? (ATTN_SCALE * LOG2E) : 1.0f;
#pragma unroll
        for (int n = 0; n < 4; n++) {
            int d = n * 16 + li;
#pragma unroll
            for (int m = 0; m < 4; m++) {
                int r0 = rowbase + wr * 64 + m * 16 + g * 4;
                int b = r0 >> 11;
                size_t base = ((size_t)(b * NHEADS + h) * SEQ) * HDIM + d;
#pragma unroll
                for (int r = 0; r < 4; r++) {
                    int s = (r0 + r) & 2047;
                    dst[base + (size_t)s * HDIM] = (unsigned short)f2bf(acc[m][n][r] * mult);
                }
            }
        }
    } else {
#pragma unroll
        for (int n = 0; n < 4; n++) {
            int d = n * 16 + li;
#pragma unroll
            for (int m = 0; m < 4; m++) {
                int r0 = rowbase + wr * 64 + m * 16 + g * 4;
                int b = r0 >> 11, s0 = r0 & 2047;
                short4v pk;
#pragma unroll
                for (int r = 0; r < 4; r++) pk[r] = f2bf(acc[m][n][r]);
                *reinterpret_cast<short4v*>(
                    &vt[((size_t)(b * NHEADS + h) * HDIM + d) * SEQ + s0]) = pk;
            }
        }
    }
}

// ---------------------------------------------------------------------------
// proj: Abf bf16 [8192][1024] x Wt bf16 [1024][1024] + bias -> out fp32
// m97 structure: BK=64 single-buffered global_load_lds
// ---------------------------------------------------------------------------
__global__ __launch_bounds__(256)
void proj_gemm_mfma(const unsigned short* __restrict__ Abf,
                    const unsigned short* __restrict__ Wt,
                    const float* __restrict__ bias, float* __restrict__ out) {
    __shared__ short Alds[128][64];
    __shared__ short Blds[128][64];
    const int tid = threadIdx.x;
    const int lane = tid & 63;
    const int wave = tid >> 6;
    const int wr = wave >> 1, wc = wave & 1;
    const int rowbase = blockIdx.y * 128;
    const int colbase = blockIdx.x * 128;
    const int g = lane >> 4, li = lane & 15;
    const int sr = lane >> 3;
    const int sc = (lane & 7) * 8;
    short* aflat = &Alds[0][0];
    short* bflat = &Blds[0][0];

    f32x4 acc[4][4];
#pragma unroll
    for (int m = 0; m < 4; m++)
#pragma unroll
        for (int n = 0; n < 4; n++) acc[m][n] = (f32x4){0.f, 0.f, 0.f, 0.f};

    for (int k0 = 0; k0 < DIMC; k0 += 64) {
#pragma unroll
        for (int e = 0; e < 4; e++) {
            int j = wave * 4 + e;
            gload16(&Abf[(size_t)(rowbase + j * 8 + sr) * DIMC + k0 + sc],
                    aflat + j * 512);
            gload16(&Wt[(size_t)(colbase + j * 8 + sr) * 1024 + k0 + sc],
                    bflat + j * 512);
        }
        __syncthreads();
#pragma unroll
        for (int ks = 0; ks < 2; ks++) {
            short8 af[4], bfr[4];
#pragma unroll
            for (int m = 0; m < 4; m++)
                af[m] = *reinterpret_cast<const short8*>(
                    &Alds[wr * 64 + m * 16 + li][ks * 32 + g * 8]);
#pragma unroll
            for (int n = 0; n < 4; n++)
                bfr[n] = *reinterpret_cast<const short8*>(
                    &Blds[wc * 64 + n * 16 + li][ks * 32 + g * 8]);
#pragma unroll
            for (int m = 0; m < 4; m++)
#pragma unroll
                for (int n = 0; n < 4; n++)
                    acc[m][n] = __builtin_amdgcn_mfma_f32_16x16x32_bf16(
                        af[m], bfr[n], acc[m][n], 0, 0, 0);
        }
        __syncthreads();
    }

#pragma unroll
    for (int n = 0; n < 4; n++) {
        int col = colbase + wc * 64 + n * 16 + li;
        float bv = bias[col];
#pragma unroll
        for (int m = 0; m < 4; m++) {
            int r0 = rowbase + wr * 64 + m * 16 + g * 4;
#pragma unroll
            for (int r = 0; r < 4; r++)
                out[(size_t)(r0 + r) * DIMC + col] = acc[m][n][r] + bv;
        }
    }
}

// ---------------------------------------------------------------------------
// MFMA flash attention (causal), exp2-domain softmax.
//  - 512 blocks, XCD-bijective swizzle (8 heads/XCD), PAIRED q-tiles {x,15-x}
//    -> every block exactly 34 KV-tiles (uniform drain; round-6 proven shell)
//  - round-8 verified inner: tree reductions, truncation bf16 pack,
//    pointer-increment staging, double-buffered K/V, issue-early loads
// ---------------------------------------------------------------------------
__global__ __launch_bounds__(256)
void flash_attn_mfma(const unsigned short* __restrict__ qg,
                     const unsigned short* __restrict__ kg,
                     const unsigned short* __restrict__ vt,
                     unsigned short* __restrict__ og) {
    __shared__ short Klds[2][64][64];
    __shared__ short Vlds[2][64][64];
    __shared__ short Plds[4][32][64];
    const int tid = threadIdx.x;
    const int lane = tid & 63;
    const int w = tid >> 6;
    const int g = lane >> 4, li = lane & 15;
    const int sw = li & 7;
    const int orig = blockIdx.x;                   // 0..511
    const int swz = (orig & 7) * 64 + (orig >> 3);
    const int bx = swz & 7;                        // q-tile pair index
    const int bh = swz >> 3;                       // head 0..63
    const size_t head = (size_t)bh * SEQ * HDIM;
    const int b = bh >> 4, h = bh & 15;

    const int c0r = tid >> 3, c0c = tid & 7;       // 32 rows; second chunk +32

    for (int pass = 0; pass < 2; pass++) {
        const int qtile = pass ? (15 - bx) : bx;
        const int qbase = qtile * 128;
        const int qw = qbase + w * 32;
        const int nt = 2 * qtile + 2;

        short8 bq[2][2];
#pragma unroll
        for (int n = 0; n < 2; n++)
#pragma unroll
            for (int ds = 0; ds < 2; ds++)
                bq[n][ds] = *reinterpret_cast<const short8*>(
                    &qg[head + (size_t)(qw + li + 16 * n) * HDIM + ds * 32 + g * 8]);

        f32x4 accO[4][2];
#pragma unroll
        for (int df = 0; df < 4; df++)
#pragma unroll
            for (int n = 0; n < 2; n++) accO[df][n] = (f32x4){0.f, 0.f, 0.f, 0.f};
        float mrow[2] = {-INFINITY, -INFINITY};
        float lrow[2] = {0.f, 0.f};

        // staging pointers (advance by constants per tile)
        const unsigned short* kp = kg + head + (size_t)c0r * HDIM + c0c * 8;
        const unsigned short* vp = vt + head + (size_t)c0r * SEQ + c0c * 8;

        short8 kreg0, kreg1, vreg0, vreg1;
        kreg0 = *reinterpret_cast<const short8*>(kp);
        kreg1 = *reinterpret_cast<const short8*>(kp + 32 * HDIM);
        vreg0 = *reinterpret_cast<const short8*>(vp);
        vreg1 = *reinterpret_cast<const short8*>(vp + 32 * SEQ);
        kp += 64 * HDIM; vp += 64;
        {
            const int sw0 = (c0c ^ (c0r & 7)) * 8;
            const int sw1 = (c0c ^ ((c0r + 32) & 7)) * 8;
            *reinterpret_cast<short8*>(&Klds[0][c0r][sw0]) = kreg0;
            *reinterpret_cast<short8*>(&Vlds[0][c0r][sw0]) = vreg0;
            *reinterpret_cast<short8*>(&Klds[0][c0r + 32][sw1]) = kreg1;
            *reinterpret_cast<short8*>(&Vlds[0][c0r + 32][sw1]) = vreg1;
        }
        __syncthreads();

        for (int t = 0; t < nt; t++) {
            const int kvbase = t * 64;
            const int buf = t & 1;
            const bool more = (t + 1 < nt);
            if (more) {      // issue next-tile loads NOW; latency hides under compute
                kreg0 = *reinterpret_cast<const short8*>(kp);
                kreg1 = *reinterpret_cast<const short8*>(kp + 32 * HDIM);
                vreg0 = *reinterpret_cast<const short8*>(vp);
                vreg1 = *reinterpret_cast<const short8*>(vp + 32 * SEQ);
                kp += 64 * HDIM; vp += 64;
            }

            if (kvbase <= qw + 31) {
                // ---- S^T = K·Q^T ----
                f32x4 s[4][2];
#pragma unroll
                for (int m = 0; m < 4; m++)
#pragma unroll
                    for (int n = 0; n < 2; n++) s[m][n] = (f32x4){0.f, 0.f, 0.f, 0.f};
#pragma unroll
                for (int ds = 0; ds < 2; ds++) {
                    short8 ak[4];
#pragma unroll
                    for (int m = 0; m < 4; m++)
                        ak[m] = *reinterpret_cast<const short8*>(
                            &Klds[buf][li + 16 * m][(((ds * 4 + g) ^ sw)) * 8]);
#pragma unroll
                    for (int m = 0; m < 4; m++)
#pragma unroll
                        for (int n = 0; n < 2; n++)
                            s[m][n] = __builtin_amdgcn_mfma_f32_16x16x32_bf16(
                                ak[m], bq[n][ds], s[m][n], 0, 0, 0);
                }
                // ---- mask (diag tiles only) ----
                const bool diag = (kvbase + 63 > qw);
                if (diag) {
#pragma unroll
                    for (int n = 0; n < 2; n++) {
                        int q = qw + li + 16 * n;
#pragma unroll
                        for (int m = 0; m < 4; m++)
#pragma unroll
                            for (int r = 0; r < 4; r++) {
                                int kv = kvbase + 16 * m + 4 * g + r;
                                if (kv > q) s[m][n][r] = -INFINITY;
                            }
                    }
                }
                // ---- tile max (tree) + corr ----
                float corr[2];
#pragma unroll
                for (int n = 0; n < 2; n++) {
                    float a0 = fmaxf(fmaxf(s[0][n][0], s[0][n][1]), fmaxf(s[0][n][2], s[0][n][3]));
                    float a1 = fmaxf(fmaxf(s[1][n][0], s[1][n][1]), fmaxf(s[1][n][2], s[1][n][3]));
                    float a2 = fmaxf(fmaxf(s[2][n][0], s[2][n][1]), fmaxf(s[2][n][2], s[2][n][3]));
                    float a3 = fmaxf(fmaxf(s[3][n][0], s[3][n][1]), fmaxf(s[3][n][2], s[3][n][3]));
                    float tm = fmaxf(fmaxf(a0, a1), fmaxf(a2, a3));
                    tm = fmaxf(tm, __shfl_xor(tm, 16));
                    tm = fmaxf(tm, __shfl_xor(tm, 32));
                    float mnew = fmaxf(mrow[n], tm);
                    corr[n] = __builtin_amdgcn_exp2f(mrow[n] - mnew);
                    mrow[n] = mnew;
                }
                // ---- P = exp2(S-m), truncation pack to LDS, partial sums ----
                float sm[4][2];
#pragma unroll
                for (int m = 0; m < 4; m++) {
#pragma unroll
                    for (int n = 0; n < 2; n++) {
                        float p0 = __builtin_amdgcn_exp2f(s[m][n][0] - mrow[n]);
                        float p1 = __builtin_amdgcn_exp2f(s[m][n][1] - mrow[n]);
                        float p2 = __builtin_amdgcn_exp2f(s[m][n][2] - mrow[n]);
                        float p3 = __builtin_amdgcn_exp2f(s[m][n][3] - mrow[n]);
                        sm[m][n] = (p0 + p1) + (p2 + p3);
                        unsigned u01 = (__float_as_uint(p1) & 0xFFFF0000u) |
                                       (__float_as_uint(p0) >> 16);
                        unsigned u23 = (__float_as_uint(p3) & 0xFFFF0000u) |
                                       (__float_as_uint(p2) >> 16);
                        *reinterpret_cast<uint2*>(
                            &Plds[w][li + 16 * n]
                                 [((2 * m + (g >> 1)) ^ sw) * 8 + (g & 1) * 4]) =
                            make_uint2(u01, u23);
                    }
                }
#pragma unroll
                for (int n = 0; n < 2; n++) {
                    float ts = (sm[0][n] + sm[1][n]) + (sm[2][n] + sm[3][n]);
                    ts += __shfl_xor(ts, 16);
                    ts += __shfl_xor(ts, 32);
                    lrow[n] = lrow[n] * corr[n] + ts;
                }
                // ---- O rescale (skipped when max unchanged across wave) ----
                bool nore = (corr[0] == 1.0f) && (corr[1] == 1.0f);
                if (!__all((int)nore)) {
#pragma unroll
                    for (int df = 0; df < 4; df++)
#pragma unroll
                        for (int n = 0; n < 2; n++) {
                            accO[df][n][0] *= corr[n]; accO[df][n][1] *= corr[n];
                            accO[df][n][2] *= corr[n]; accO[df][n][3] *= corr[n];
                        }
                }
                // ---- O^T += V^T·P^T ----
#pragma unroll
                for (int ks = 0; ks < 2; ks++) {
                    short8 av[4], bp[2];
#pragma unroll
                    for (int df = 0; df < 4; df++)
                        av[df] = *reinterpret_cast<const short8*>(
                            &Vlds[buf][li + 16 * df][((ks * 4 + g) ^ sw) * 8]);
#pragma unroll
                    for (int n = 0; n < 2; n++)
                        bp[n] = *reinterpret_cast<const short8*>(
                            &Plds[w][li + 16 * n][((ks * 4 + g) ^ sw) * 8]);
#pragma unroll
                    for (int df = 0; df < 4; df++)
#pragma unroll
                        for (int n = 0; n < 2; n++)
                            accO[df][n] = __builtin_amdgcn_mfma_f32_16x16x32_bf16(
                                av[df], bp[n], accO[df][n], 0, 0, 0);
                }
            }

            if (more) {
                const int nbuf = buf ^ 1;
                const int sw0 = (c0c ^ (c0r & 7)) * 8;
                const int sw1 = (c0c ^ ((c0r + 32) & 7)) * 8;
                *reinterpret_cast<short8*>(&Klds[nbuf][c0r][sw0]) = kreg0;
                *reinterpret_cast<short8*>(&Vlds[nbuf][c0r][sw0]) = vreg0;
                *reinterpret_cast<short8*>(&Klds[nbuf][c0r + 32][sw1]) = kreg1;
                *reinterpret_cast<short8*>(&Vlds[nbuf][c0r + 32][sw1]) = vreg1;
            }
            __syncthreads();
        }

        // epilogue: O[q][d] = accO^T / l
#pragma unroll
        for (int n = 0; n < 2; n++) {
            float inv = 1.0f / lrow[n];
            int q = qw + li + 16 * n;
            size_t rowoff = (size_t)(b * SEQ + q) * DIMC + h * HDIM;
#pragma unroll
            for (int df = 0; df < 4; df++) {
                short4v pk;
#pragma unroll
                for (int r = 0; r < 4; r++) pk[r] = f2bf(accO[df][n][r] * inv);
                *reinterpret_cast<short4v*>(&og[rowoff + 16 * df + 4 * g]) = pk;
            }
        }
        __syncthreads();   // protect LDS before next pass's prologue writes
    }
}

extern "C" void kernel_launch(void* const* d_in, const int* in_sizes, int n_in,
                              void* d_out, int out_size, void* d_ws, size_t ws_size,
                              hipStream_t stream) {
    const float* x      = (const float*)d_in[0];   // [4,2048,1024]
    const float* w_qkv  = (const float*)d_in[1];   // [1024,3072]
    const float* w_proj = (const float*)d_in[2];   // [1024,1024]
    const float* b_proj = (const float*)d_in[3];   // [1024]
    float* out = (float*)d_out;                    // [4,2048,1024] fp32

    char* w = (char*)d_ws;
    unsigned short* qb  = (unsigned short*)(w);                        // 16 MB
    unsigned short* kb  = (unsigned short*)(w + ((size_t)16 << 20));   // 16 MB
    unsigned short* vtb = (unsigned short*)(w + ((size_t)32 << 20));   // 16 MB [B,H,D,S]
    unsigned short* ao  = (unsigned short*)(w + ((size_t)48 << 20));   // 16 MB
    unsigned short* wqt = (unsigned short*)(w + ((size_t)64 << 20));   // 6 MB
    unsigned short* wpt = (unsigned short*)(w + ((size_t)72 << 20));   // 2 MB
    unsigned short* xbf = (unsigned short*)(w + ((size_t)80 << 20));   // 16 MB

    xcvt<<<NROWS * DIMC / (256 * 8), 256, 0, stream>>>(x, xbf);
    transpose_cvt<<<dim3(3 * DIMC / 64, DIMC / 64), 256, 0, stream>>>(w_qkv, wqt, 3 * DIMC);
    transpose_cvt<<<dim3(DIMC / 64, DIMC / 64), 256, 0, stream>>>(w_proj, wpt, DIMC);
    qkv_gemm_mfma<<<dim3(3 * DIMC / 128, NROWS / 128), 256, 0, stream>>>(xbf, wqt, qb, kb, vtb);
    flash_attn_mfma<<<512, 256, 0, stream>>>(qb, kb, vtb, ao);
    proj_gemm_mfma<<<dim3(DIMC / 128, NROWS / 128), 256, 0, stream>>>(ao, wpt, b_proj, out);
}

// Round 10
// 250.672 us; speedup vs baseline: 1.1952x; 1.1158x over previous
//
#include <hip/hip_runtime.h>
#include <hip/hip_bf16.h>
#include <math.h>

#define DIMC 1024
#define NHEADS 16
#define HDIM 64
#define BATCH 4
#define SEQ 2048
#define NROWS (BATCH * SEQ)      // 8192
#define ATTN_SCALE 0.125f        // 64^-0.5
#define LOG2E 1.4426950408889634f

typedef __attribute__((ext_vector_type(8))) short short8;   // 8 bf16 = 4 VGPR
typedef __attribute__((ext_vector_type(4))) short short4v;  // 4 bf16 = 2 VGPR
typedef __attribute__((ext_vector_type(4))) float f32x4;    // MFMA C/D

static __device__ __forceinline__ short f2bf(float f) {
    __hip_bfloat16 h = __float2bfloat16(f);
    return *reinterpret_cast<short*>(&h);
}

// async global->LDS, 16B per lane; LDS dest = wave-uniform base + lane*16
static __device__ __forceinline__ void gload16(const void* g, void* l) {
    __builtin_amdgcn_global_load_lds(
        (const __attribute__((address_space(1))) unsigned int*)g,
        (__attribute__((address_space(3))) unsigned int*)l, 16, 0, 0);
}

// ---------------------------------------------------------------------------
// X fp32 -> bf16 (row-major copy), 8 elems/thread
// ---------------------------------------------------------------------------
__global__ __launch_bounds__(256)
void xcvt(const float* __restrict__ in, unsigned short* __restrict__ out) {
    int i = blockIdx.x * 256 + threadIdx.x;
    const float4* p = reinterpret_cast<const float4*>(in) + 2 * i;
    float4 a = p[0], b = p[1];
    short8 pk;
    pk[0] = f2bf(a.x); pk[1] = f2bf(a.y); pk[2] = f2bf(a.z); pk[3] = f2bf(a.w);
    pk[4] = f2bf(b.x); pk[5] = f2bf(b.y); pk[6] = f2bf(b.z); pk[7] = f2bf(b.w);
    reinterpret_cast<short8*>(out)[i] = pk;
}

// ---------------------------------------------------------------------------
// transpose + fp32->bf16: src fp32 [1024][N] -> dst bf16 [N][1024]
// ---------------------------------------------------------------------------
__global__ __launch_bounds__(256)
void transpose_cvt(const float* __restrict__ src, unsigned short* __restrict__ dst,
                   int N) {
    __shared__ float t[64][65];
    const int tid = threadIdx.x;
    const int cb = blockIdx.x * 64;
    const int rb = blockIdx.y * 64;
#pragma unroll
    for (int e = 0; e < 4; e++) {
        int idx = tid + e * 256;
        int row = idx >> 4;
        int c4 = (idx & 15) << 2;
        *reinterpret_cast<float4*>(&t[row][c4]) =
            *reinterpret_cast<const float4*>(&src[(size_t)(rb + row) * N + cb + c4]);
    }
    __syncthreads();
#pragma unroll
    for (int e = 0; e < 2; e++) {
        int idx = tid + e * 256;
        int col = idx >> 3;
        int k8 = (idx & 7) << 3;
        short8 pk;
#pragma unroll
        for (int j = 0; j < 8; j++) pk[j] = f2bf(t[k8 + j][col]);
        *reinterpret_cast<short8*>(&dst[(size_t)(cb + col) * 1024 + rb + k8]) = pk;
    }
}

// ---------------------------------------------------------------------------
// qkv: Xbf bf16 [8192][1024] x Wt bf16 [3072][1024] -> bf16 q,k [B,H,S,D], vt [B,H,D,S]
// BK=64 global_load_lds; XOR-swizzled LDS (pre-swizzled global src + swz read)
// ---------------------------------------------------------------------------
__global__ __launch_bounds__(256)
void qkv_gemm_mfma(const unsigned short* __restrict__ Xbf,
                   const unsigned short* __restrict__ Wt,
                   unsigned short* __restrict__ qo, unsigned short* __restrict__ ko,
                   unsigned short* __restrict__ vt) {
    __shared__ short Alds[128][64];   // 16 KB
    __shared__ short Blds[128][64];   // 16 KB
    const int tid = threadIdx.x;
    const int lane = tid & 63;
    const int wave = tid >> 6;
    const int wr = wave >> 1, wc = wave & 1;
    const int rowbase = blockIdx.y * 128;
    const int colbase = blockIdx.x * 128;
    const int g = lane >> 4, li = lane & 15;
    const int sr = lane >> 3;                       // 0..7 row within 8-row chunk
    const int sc = ((lane & 7) ^ sr) * 8;           // pre-swizzled global chunk
    const int swk = li & 7;                         // read-side swizzle key
    short* aflat = &Alds[0][0];
    short* bflat = &Blds[0][0];

    f32x4 acc[4][4];
#pragma unroll
    for (int m = 0; m < 4; m++)
#pragma unroll
        for (int n = 0; n < 4; n++) acc[m][n] = (f32x4){0.f, 0.f, 0.f, 0.f};

    for (int k0 = 0; k0 < DIMC; k0 += 64) {
#pragma unroll
        for (int e = 0; e < 4; e++) {
            int j = wave * 4 + e;      // 0..15: 8-row chunk index
            gload16(&Xbf[(size_t)(rowbase + j * 8 + sr) * DIMC + k0 + sc],
                    aflat + j * 512);
            gload16(&Wt[(size_t)(colbase + j * 8 + sr) * 1024 + k0 + sc],
                    bflat + j * 512);
        }
        __syncthreads();
#pragma unroll
        for (int ks = 0; ks < 2; ks++) {
            short8 af[4], bfr[4];
#pragma unroll
            for (int m = 0; m < 4; m++)
                af[m] = *reinterpret_cast<const short8*>(
                    &Alds[wr * 64 + m * 16 + li][((ks * 4 + g) ^ swk) * 8]);
#pragma unroll
            for (int n = 0; n < 4; n++)
                bfr[n] = *reinterpret_cast<const short8*>(
                    &Blds[wc * 64 + n * 16 + li][((ks * 4 + g) ^ swk) * 8]);
#pragma unroll
            for (int m = 0; m < 4; m++)
#pragma unroll
                for (int n = 0; n < 4; n++)
                    acc[m][n] = __builtin_amdgcn_mfma_f32_16x16x32_bf16(
                        af[m], bfr[n], acc[m][n], 0, 0, 0);
        }
        __syncthreads();
    }

    const int col0 = colbase + wc * 64;
    const int three = col0 >> 10;
    const int h = (col0 & 1023) >> 6;
    if (three < 2) {
        unsigned short* dst = (three == 0) ? qo : ko;
        const float mult = (three == 0) ? (ATTN_SCALE * LOG2E) : 1.0f;
#pragma unroll
        for (int n = 0; n < 4; n++) {
            int d = n * 16 + li;
#pragma unroll
            for (int m = 0; m < 4; m++) {
                int r0 = rowbase + wr * 64 + m * 16 + g * 4;
                int b = r0 >> 11;
                size_t base = ((size_t)(b * NHEADS + h) * SEQ) * HDIM + d;
#pragma unroll
                for (int r = 0; r < 4; r++) {
                    int s = (r0 + r) & 2047;
                    dst[base + (size_t)s * HDIM] = (unsigned short)f2bf(acc[m][n][r] * mult);
                }
            }
        }
    } else {
#pragma unroll
        for (int n = 0; n < 4; n++) {
            int d = n * 16 + li;
#pragma unroll
            for (int m = 0; m < 4; m++) {
                int r0 = rowbase + wr * 64 + m * 16 + g * 4;
                int b = r0 >> 11, s0 = r0 & 2047;
                short4v pk;
#pragma unroll
                for (int r = 0; r < 4; r++) pk[r] = f2bf(acc[m][n][r]);
                *reinterpret_cast<short4v*>(
                    &vt[((size_t)(b * NHEADS + h) * HDIM + d) * SEQ + s0]) = pk;
            }
        }
    }
}

// ---------------------------------------------------------------------------
// proj: Abf bf16 [8192][1024] x Wt bf16 [1024][1024] + bias -> out fp32
// BK=64 global_load_lds; XOR-swizzled LDS
// ---------------------------------------------------------------------------
__global__ __launch_bounds__(256)
void proj_gemm_mfma(const unsigned short* __restrict__ Abf,
                    const unsigned short* __restrict__ Wt,
                    const float* __restrict__ bias, float* __restrict__ out) {
    __shared__ short Alds[128][64];
    __shared__ short Blds[128][64];
    const int tid = threadIdx.x;
    const int lane = tid & 63;
    const int wave = tid >> 6;
    const int wr = wave >> 1, wc = wave & 1;
    const int rowbase = blockIdx.y * 128;
    const int colbase = blockIdx.x * 128;
    const int g = lane >> 4, li = lane & 15;
    const int sr = lane >> 3;
    const int sc = ((lane & 7) ^ sr) * 8;
    const int swk = li & 7;
    short* aflat = &Alds[0][0];
    short* bflat = &Blds[0][0];

    f32x4 acc[4][4];
#pragma unroll
    for (int m = 0; m < 4; m++)
#pragma unroll
        for (int n = 0; n < 4; n++) acc[m][n] = (f32x4){0.f, 0.f, 0.f, 0.f};

    for (int k0 = 0; k0 < DIMC; k0 += 64) {
#pragma unroll
        for (int e = 0; e < 4; e++) {
            int j = wave * 4 + e;
            gload16(&Abf[(size_t)(rowbase + j * 8 + sr) * DIMC + k0 + sc],
                    aflat + j * 512);
            gload16(&Wt[(size_t)(colbase + j * 8 + sr) * 1024 + k0 + sc],
                    bflat + j * 512);
        }
        __syncthreads();
#pragma unroll
        for (int ks = 0; ks < 2; ks++) {
            short8 af[4], bfr[4];
#pragma unroll
            for (int m = 0; m < 4; m++)
                af[m] = *reinterpret_cast<const short8*>(
                    &Alds[wr * 64 + m * 16 + li][((ks * 4 + g) ^ swk) * 8]);
#pragma unroll
            for (int n = 0; n < 4; n++)
                bfr[n] = *reinterpret_cast<const short8*>(
                    &Blds[wc * 64 + n * 16 + li][((ks * 4 + g) ^ swk) * 8]);
#pragma unroll
            for (int m = 0; m < 4; m++)
#pragma unroll
                for (int n = 0; n < 4; n++)
                    acc[m][n] = __builtin_amdgcn_mfma_f32_16x16x32_bf16(
                        af[m], bfr[n], acc[m][n], 0, 0, 0);
        }
        __syncthreads();
    }

#pragma unroll
    for (int n = 0; n < 4; n++) {
        int col = colbase + wc * 64 + n * 16 + li;
        float bv = bias[col];
#pragma unroll
        for (int m = 0; m < 4; m++) {
            int r0 = rowbase + wr * 64 + m * 16 + g * 4;
#pragma unroll
            for (int r = 0; r < 4; r++)
                out[(size_t)(r0 + r) * DIMC + col] = acc[m][n][r] + bv;
        }
    }
}

// ---------------------------------------------------------------------------
// MFMA flash attention (causal), exp2-domain softmax.
//  - 8 waves x 16 q-rows (512 threads): per-thread softmax work halved vs
//    4-wave version, 24 waves/CU residency (was 12) -> latency hiding
//  - 512 blocks, XCD-bijective swizzle, PAIRED q-tiles {x,15-x} (uniform drain)
//  - tree reductions, truncation bf16 pack, pointer-increment staging,
//    double-buffered K/V, issue-early loads
// ---------------------------------------------------------------------------
__global__ __launch_bounds__(512)
void flash_attn_mfma(const unsigned short* __restrict__ qg,
                     const unsigned short* __restrict__ kg,
                     const unsigned short* __restrict__ vt,
                     unsigned short* __restrict__ og) {
    __shared__ short Klds[2][64][64];   // 16 KB
    __shared__ short Vlds[2][64][64];   // 16 KB
    __shared__ short Plds[8][16][64];   // 16 KB
    const int tid = threadIdx.x;
    const int lane = tid & 63;
    const int w = tid >> 6;             // 0..7
    const int g = lane >> 4, li = lane & 15;
    const int sw = li & 7;
    const int orig = blockIdx.x;                   // 0..511
    const int swz = (orig & 7) * 64 + (orig >> 3);
    const int bx = swz & 7;                        // q-tile pair index
    const int bh = swz >> 3;                       // head 0..63
    const size_t head = (size_t)bh * SEQ * HDIM;
    const int b = bh >> 4, h = bh & 15;

    const int c0r = tid >> 3, c0c = tid & 7;       // one 16B chunk per thread

    for (int pass = 0; pass < 2; pass++) {
        const int qtile = pass ? (15 - bx) : bx;
        const int qbase = qtile * 128;
        const int qw = qbase + w * 16;             // 16 q-rows per wave
        const int nt = 2 * qtile + 2;

        // Q fragment: col q=li, k d=32*ds+8g+j
        short8 bq[2];
#pragma unroll
        for (int ds = 0; ds < 2; ds++)
            bq[ds] = *reinterpret_cast<const short8*>(
                &qg[head + (size_t)(qw + li) * HDIM + ds * 32 + g * 8]);

        f32x4 accO[4];
#pragma unroll
        for (int df = 0; df < 4; df++) accO[df] = (f32x4){0.f, 0.f, 0.f, 0.f};
        float mrow = -INFINITY;
        float lrow = 0.f;

        const unsigned short* kp = kg + head + (size_t)c0r * HDIM + c0c * 8;
        const unsigned short* vp = vt + head + (size_t)c0r * SEQ + c0c * 8;

        short8 kreg, vreg;
        kreg = *reinterpret_cast<const short8*>(kp);
        vreg = *reinterpret_cast<const short8*>(vp);
        kp += 64 * HDIM; vp += 64;
        {
            const int sw0 = (c0c ^ (c0r & 7)) * 8;
            *reinterpret_cast<short8*>(&Klds[0][c0r][sw0]) = kreg;
            *reinterpret_cast<short8*>(&Vlds[0][c0r][sw0]) = vreg;
        }
        __syncthreads();

        for (int t = 0; t < nt; t++) {
            const int kvbase = t * 64;
            const int buf = t & 1;
            const bool more = (t + 1 < nt);
            if (more) {      // issue next-tile loads NOW
                kreg = *reinterpret_cast<const short8*>(kp);
                vreg = *reinterpret_cast<const short8*>(vp);
                kp += 64 * HDIM; vp += 64;
            }

            if (kvbase <= qw + 15) {     // wave-uniform causal skip
                // ---- S^T = K·Q^T :  D[kv=16m+4g+r][q=li] ----
                f32x4 s[4];
#pragma unroll
                for (int m = 0; m < 4; m++) s[m] = (f32x4){0.f, 0.f, 0.f, 0.f};
#pragma unroll
                for (int ds = 0; ds < 2; ds++) {
                    short8 ak[4];
#pragma unroll
                    for (int m = 0; m < 4; m++)
                        ak[m] = *reinterpret_cast<const short8*>(
                            &Klds[buf][li + 16 * m][((ds * 4 + g) ^ sw) * 8]);
#pragma unroll
                    for (int m = 0; m < 4; m++)
                        s[m] = __builtin_amdgcn_mfma_f32_16x16x32_bf16(
                            ak[m], bq[ds], s[m], 0, 0, 0);
                }
                // ---- mask (diag tiles only) ----
                const bool diag = (kvbase + 63 > qw);
                if (diag) {
                    int q = qw + li;
#pragma unroll
                    for (int m = 0; m < 4; m++)
#pragma unroll
                        for (int r = 0; r < 4; r++) {
                            int kv = kvbase + 16 * m + 4 * g + r;
                            if (kv > q) s[m][r] = -INFINITY;
                        }
                }
                // ---- tile max (tree) + corr ----
                float a0 = fmaxf(fmaxf(s[0][0], s[0][1]), fmaxf(s[0][2], s[0][3]));
                float a1 = fmaxf(fmaxf(s[1][0], s[1][1]), fmaxf(s[1][2], s[1][3]));
                float a2 = fmaxf(fmaxf(s[2][0], s[2][1]), fmaxf(s[2][2], s[2][3]));
                float a3 = fmaxf(fmaxf(s[3][0], s[3][1]), fmaxf(s[3][2], s[3][3]));
                float tm = fmaxf(fmaxf(a0, a1), fmaxf(a2, a3));
                tm = fmaxf(tm, __shfl_xor(tm, 16));
                tm = fmaxf(tm, __shfl_xor(tm, 32));
                float mnew = fmaxf(mrow, tm);
                float corr = __builtin_amdgcn_exp2f(mrow - mnew);
                mrow = mnew;
                // ---- P = exp2(S-m), truncation pack to LDS, partial sums ----
                float sm[4];
#pragma unroll
                for (int m = 0; m < 4; m++) {
                    float p0 = __builtin_amdgcn_exp2f(s[m][0] - mrow);
                    float p1 = __builtin_amdgcn_exp2f(s[m][1] - mrow);
                    float p2 = __builtin_amdgcn_exp2f(s[m][2] - mrow);
                    float p3 = __builtin_amdgcn_exp2f(s[m][3] - mrow);
                    sm[m] = (p0 + p1) + (p2 + p3);
                    unsigned u01 = (__float_as_uint(p1) & 0xFFFF0000u) |
                                   (__float_as_uint(p0) >> 16);
                    unsigned u23 = (__float_as_uint(p3) & 0xFFFF0000u) |
                                   (__float_as_uint(p2) >> 16);
                    *reinterpret_cast<uint2*>(
                        &Plds[w][li][((2 * m + (g >> 1)) ^ sw) * 8 + (g & 1) * 4]) =
                        make_uint2(u01, u23);
                }
                float ts = (sm[0] + sm[1]) + (sm[2] + sm[3]);
                ts += __shfl_xor(ts, 16);
                ts += __shfl_xor(ts, 32);
                lrow = lrow * corr + ts;
                // ---- O rescale (skipped when max unchanged across wave) ----
                if (!__all((int)(corr == 1.0f))) {
#pragma unroll
                    for (int df = 0; df < 4; df++) {
                        accO[df][0] *= corr; accO[df][1] *= corr;
                        accO[df][2] *= corr; accO[df][3] *= corr;
                    }
                }
                // ---- O^T += V^T·P^T :  D[d=16df+4g+r][q=li] ----
#pragma unroll
                for (int ks = 0; ks < 2; ks++) {
                    short8 av[4];
#pragma unroll
                    for (int df = 0; df < 4; df++)
                        av[df] = *reinterpret_cast<const short8*>(
                            &Vlds[buf][li + 16 * df][((ks * 4 + g) ^ sw) * 8]);
                    short8 bp = *reinterpret_cast<const short8*>(
                        &Plds[w][li][((ks * 4 + g) ^ sw) * 8]);
#pragma unroll
                    for (int df = 0; df < 4; df++)
                        accO[df] = __builtin_amdgcn_mfma_f32_16x16x32_bf16(
                            av[df], bp, accO[df], 0, 0, 0);
                }
            }

            if (more) {
                const int nbuf = buf ^ 1;
                const int sw0 = (c0c ^ (c0r & 7)) * 8;
                *reinterpret_cast<short8*>(&Klds[nbuf][c0r][sw0]) = kreg;
                *reinterpret_cast<short8*>(&Vlds[nbuf][c0r][sw0]) = vreg;
            }
            __syncthreads();
        }

        // epilogue: O[q][d] = accO^T / l
        {
            float inv = 1.0f / lrow;
            int q = qw + li;
            size_t rowoff = (size_t)(b * SEQ + q) * DIMC + h * HDIM;
#pragma unroll
            for (int df = 0; df < 4; df++) {
                short4v pk;
#pragma unroll
                for (int r = 0; r < 4; r++) pk[r] = f2bf(accO[df][r] * inv);
                *reinterpret_cast<short4v*>(&og[rowoff + 16 * df + 4 * g]) = pk;
            }
        }
        __syncthreads();   // protect LDS before next pass's prologue writes
    }
}

extern "C" void kernel_launch(void* const* d_in, const int* in_sizes, int n_in,
                              void* d_out, int out_size, void* d_ws, size_t ws_size,
                              hipStream_t stream) {
    const float* x      = (const float*)d_in[0];   // [4,2048,1024]
    const float* w_qkv  = (const float*)d_in[1];   // [1024,3072]
    const float* w_proj = (const float*)d_in[2];   // [1024,1024]
    const float* b_proj = (const float*)d_in[3];   // [1024]
    float* out = (float*)d_out;                    // [4,2048,1024] fp32

    char* w = (char*)d_ws;
    unsigned short* qb  = (unsigned short*)(w);                        // 16 MB
    unsigned short* kb  = (unsigned short*)(w + ((size_t)16 << 20));   // 16 MB
    unsigned short* vtb = (unsigned short*)(w + ((size_t)32 << 20));   // 16 MB [B,H,D,S]
    unsigned short* ao  = (unsigned short*)(w + ((size_t)48 << 20));   // 16 MB
    unsigned short* wqt = (unsigned short*)(w + ((size_t)64 << 20));   // 6 MB
    unsigned short* wpt = (unsigned short*)(w + ((size_t)72 << 20));   // 2 MB
    unsigned short* xbf = (unsigned short*)(w + ((size_t)80 << 20));   // 16 MB

    xcvt<<<NROWS * DIMC / (256 * 8), 256, 0, stream>>>(x, xbf);
    transpose_cvt<<<dim3(3 * DIMC / 64, DIMC / 64), 256, 0, stream>>>(w_qkv, wqt, 3 * DIMC);
    transpose_cvt<<<dim3(DIMC / 64, DIMC / 64), 256, 0, stream>>>(w_proj, wpt, DIMC);
    qkv_gemm_mfma<<<dim3(3 * DIMC / 128, NROWS / 128), 256, 0, stream>>>(xbf, wqt, qb, kb, vtb);
    flash_attn_mfma<<<512, 512, 0, stream>>>(qb, kb, vtb, ao);
    proj_gemm_mfma<<<dim3(DIMC / 128, NROWS / 128), 256, 0, stream>>>(ao, wpt, b_proj, out);
}

// Round 11
// 247.601 us; speedup vs baseline: 1.2100x; 1.0124x over previous
//
#include <hip/hip_runtime.h>
#include <hip/hip_bf16.h>
#include <math.h>

#define DIMC 1024
#define NHEADS 16
#define HDIM 64
#define BATCH 4
#define SEQ 2048
#define NROWS (BATCH * SEQ)      // 8192
#define ATTN_SCALE 0.125f        // 64^-0.5
#define LOG2E 1.4426950408889634f

typedef __attribute__((ext_vector_type(8))) short short8;   // 8 bf16 = 4 VGPR
typedef __attribute__((ext_vector_type(4))) short short4v;  // 4 bf16 = 2 VGPR
typedef __attribute__((ext_vector_type(4))) float f32x4;    // MFMA C/D

static __device__ __forceinline__ short f2bf(float f) {
    __hip_bfloat16 h = __float2bfloat16(f);
    return *reinterpret_cast<short*>(&h);
}

// async global->LDS, 16B per lane; LDS dest = wave-uniform base + lane*16
static __device__ __forceinline__ void gload16(const void* g, void* l) {
    __builtin_amdgcn_global_load_lds(
        (const __attribute__((address_space(1))) unsigned int*)g,
        (__attribute__((address_space(3))) unsigned int*)l, 16, 0, 0);
}

// ---------------------------------------------------------------------------
// X fp32 -> bf16 (row-major copy), 8 elems/thread
// ---------------------------------------------------------------------------
__global__ __launch_bounds__(256)
void xcvt(const float* __restrict__ in, unsigned short* __restrict__ out) {
    int i = blockIdx.x * 256 + threadIdx.x;
    const float4* p = reinterpret_cast<const float4*>(in) + 2 * i;
    float4 a = p[0], b = p[1];
    short8 pk;
    pk[0] = f2bf(a.x); pk[1] = f2bf(a.y); pk[2] = f2bf(a.z); pk[3] = f2bf(a.w);
    pk[4] = f2bf(b.x); pk[5] = f2bf(b.y); pk[6] = f2bf(b.z); pk[7] = f2bf(b.w);
    reinterpret_cast<short8*>(out)[i] = pk;
}

// ---------------------------------------------------------------------------
// transpose + fp32->bf16: src fp32 [1024][N] -> dst bf16 [N][1024]
// ---------------------------------------------------------------------------
__global__ __launch_bounds__(256)
void transpose_cvt(const float* __restrict__ src, unsigned short* __restrict__ dst,
                   int N) {
    __shared__ float t[64][65];
    const int tid = threadIdx.x;
    const int cb = blockIdx.x * 64;
    const int rb = blockIdx.y * 64;
#pragma unroll
    for (int e = 0; e < 4; e++) {
        int idx = tid + e * 256;
        int row = idx >> 4;
        int c4 = (idx & 15) << 2;
        *reinterpret_cast<float4*>(&t[row][c4]) =
            *reinterpret_cast<const float4*>(&src[(size_t)(rb + row) * N + cb + c4]);
    }
    __syncthreads();
#pragma unroll
    for (int e = 0; e < 2; e++) {
        int idx = tid + e * 256;
        int col = idx >> 3;
        int k8 = (idx & 7) << 3;
        short8 pk;
#pragma unroll
        for (int j = 0; j < 8; j++) pk[j] = f2bf(t[k8 + j][col]);
        *reinterpret_cast<short8*>(&dst[(size_t)(cb + col) * 1024 + rb + k8]) = pk;
    }
}

// ---------------------------------------------------------------------------
// qkv: Xbf bf16 [8192][1024] x Wt bf16 [3072][1024] -> bf16 q,k [B,H,S,D], vt [B,H,D,S]
// BK=64 global_load_lds; XOR-swizzled LDS (pre-swizzled global src + swz read)
// ---------------------------------------------------------------------------
__global__ __launch_bounds__(256)
void qkv_gemm_mfma(const unsigned short* __restrict__ Xbf,
                   const unsigned short* __restrict__ Wt,
                   unsigned short* __restrict__ qo, unsigned short* __restrict__ ko,
                   unsigned short* __restrict__ vt) {
    __shared__ short Alds[128][64];   // 16 KB
    __shared__ short Blds[128][64];   // 16 KB
    const int tid = threadIdx.x;
    const int lane = tid & 63;
    const int wave = tid >> 6;
    const int wr = wave >> 1, wc = wave & 1;
    const int rowbase = blockIdx.y * 128;
    const int colbase = blockIdx.x * 128;
    const int g = lane >> 4, li = lane & 15;
    const int sr = lane >> 3;                       // 0..7 row within 8-row chunk
    const int sc = ((lane & 7) ^ sr) * 8;           // pre-swizzled global chunk
    const int swk = li & 7;                         // read-side swizzle key
    short* aflat = &Alds[0][0];
    short* bflat = &Blds[0][0];

    f32x4 acc[4][4];
#pragma unroll
    for (int m = 0; m < 4; m++)
#pragma unroll
        for (int n = 0; n < 4; n++) acc[m][n] = (f32x4){0.f, 0.f, 0.f, 0.f};

    for (int k0 = 0; k0 < DIMC; k0 += 64) {
#pragma unroll
        for (int e = 0; e < 4; e++) {
            int j = wave * 4 + e;      // 0..15: 8-row chunk index
            gload16(&Xbf[(size_t)(rowbase + j * 8 + sr) * DIMC + k0 + sc],
                    aflat + j * 512);
            gload16(&Wt[(size_t)(colbase + j * 8 + sr) * 1024 + k0 + sc],
                    bflat + j * 512);
        }
        __syncthreads();
#pragma unroll
        for (int ks = 0; ks < 2; ks++) {
            short8 af[4], bfr[4];
#pragma unroll
            for (int m = 0; m < 4; m++)
                af[m] = *reinterpret_cast<const short8*>(
                    &Alds[wr * 64 + m * 16 + li][((ks * 4 + g) ^ swk) * 8]);
#pragma unroll
            for (int n = 0; n < 4; n++)
                bfr[n] = *reinterpret_cast<const short8*>(
                    &Blds[wc * 64 + n * 16 + li][((ks * 4 + g) ^ swk) * 8]);
#pragma unroll
            for (int m = 0; m < 4; m++)
#pragma unroll
                for (int n = 0; n < 4; n++)
                    acc[m][n] = __builtin_amdgcn_mfma_f32_16x16x32_bf16(
                        af[m], bfr[n], acc[m][n], 0, 0, 0);
        }
        __syncthreads();
    }

    const int col0 = colbase + wc * 64;
    const int three = col0 >> 10;
    const int h = (col0 & 1023) >> 6;
    if (three < 2) {
        unsigned short* dst = (three == 0) ? qo : ko;
        const float mult = (three == 0) ? (ATTN_SCALE * LOG2E) : 1.0f;
#pragma unroll
        for (int n = 0; n < 4; n++) {
            int d = n * 16 + li;
#pragma unroll
            for (int m = 0; m < 4; m++) {
                int r0 = rowbase + wr * 64 + m * 16 + g * 4;
                int b = r0 >> 11;
                size_t base = ((size_t)(b * NHEADS + h) * SEQ) * HDIM + d;
#pragma unroll
                for (int r = 0; r < 4; r++) {
                    int s = (r0 + r) & 2047;
                    dst[base + (size_t)s * HDIM] = (unsigned short)f2bf(acc[m][n][r] * mult);
                }
            }
        }
    } else {
#pragma unroll
        for (int n = 0; n < 4; n++) {
            int d = n * 16 + li;
#pragma unroll
            for (int m = 0; m < 4; m++) {
                int r0 = rowbase + wr * 64 + m * 16 + g * 4;
                int b = r0 >> 11, s0 = r0 & 2047;
                short4v pk;
#pragma unroll
                for (int r = 0; r < 4; r++) pk[r] = f2bf(acc[m][n][r]);
                *reinterpret_cast<short4v*>(
                    &vt[((size_t)(b * NHEADS + h) * HDIM + d) * SEQ + s0]) = pk;
            }
        }
    }
}

// ---------------------------------------------------------------------------
// proj: Abf bf16 [8192][1024] x Wt bf16 [1024][1024] + bias -> out fp32
// BK=64 global_load_lds; XOR-swizzled LDS
// ---------------------------------------------------------------------------
__global__ __launch_bounds__(256)
void proj_gemm_mfma(const unsigned short* __restrict__ Abf,
                    const unsigned short* __restrict__ Wt,
                    const float* __restrict__ bias, float* __restrict__ out) {
    __shared__ short Alds[128][64];
    __shared__ short Blds[128][64];
    const int tid = threadIdx.x;
    const int lane = tid & 63;
    const int wave = tid >> 6;
    const int wr = wave >> 1, wc = wave & 1;
    const int rowbase = blockIdx.y * 128;
    const int colbase = blockIdx.x * 128;
    const int g = lane >> 4, li = lane & 15;
    const int sr = lane >> 3;
    const int sc = ((lane & 7) ^ sr) * 8;
    const int swk = li & 7;
    short* aflat = &Alds[0][0];
    short* bflat = &Blds[0][0];

    f32x4 acc[4][4];
#pragma unroll
    for (int m = 0; m < 4; m++)
#pragma unroll
        for (int n = 0; n < 4; n++) acc[m][n] = (f32x4){0.f, 0.f, 0.f, 0.f};

    for (int k0 = 0; k0 < DIMC; k0 += 64) {
#pragma unroll
        for (int e = 0; e < 4; e++) {
            int j = wave * 4 + e;
            gload16(&Abf[(size_t)(rowbase + j * 8 + sr) * DIMC + k0 + sc],
                    aflat + j * 512);
            gload16(&Wt[(size_t)(colbase + j * 8 + sr) * 1024 + k0 + sc],
                    bflat + j * 512);
        }
        __syncthreads();
#pragma unroll
        for (int ks = 0; ks < 2; ks++) {
            short8 af[4], bfr[4];
#pragma unroll
            for (int m = 0; m < 4; m++)
                af[m] = *reinterpret_cast<const short8*>(
                    &Alds[wr * 64 + m * 16 + li][((ks * 4 + g) ^ swk) * 8]);
#pragma unroll
            for (int n = 0; n < 4; n++)
                bfr[n] = *reinterpret_cast<const short8*>(
                    &Blds[wc * 64 + n * 16 + li][((ks * 4 + g) ^ swk) * 8]);
#pragma unroll
            for (int m = 0; m < 4; m++)
#pragma unroll
                for (int n = 0; n < 4; n++)
                    acc[m][n] = __builtin_amdgcn_mfma_f32_16x16x32_bf16(
                        af[m], bfr[n], acc[m][n], 0, 0, 0);
        }
        __syncthreads();
    }

#pragma unroll
    for (int n = 0; n < 4; n++) {
        int col = colbase + wc * 64 + n * 16 + li;
        float bv = bias[col];
#pragma unroll
        for (int m = 0; m < 4; m++) {
            int r0 = rowbase + wr * 64 + m * 16 + g * 4;
#pragma unroll
            for (int r = 0; r < 4; r++)
                out[(size_t)(r0 + r) * DIMC + col] = acc[m][n][r] + bv;
        }
    }
}

// ---------------------------------------------------------------------------
// MFMA flash attention (causal), exp2-domain softmax.
//  - 8 waves x 16 q-rows, 512 threads; 512 blocks XCD-swizzled, paired q-tiles
//  - PERMUTED QK^T A-rows: ak[m] reads K rows 32(m>>1)+8(li>>2)+4(m&1)+(li&3),
//    so lane (g,li) holds S/P at kv=32ks+8g+j -> PV B-operand is LANE-LOCAL.
//    Plds eliminated (LDS 48->32KB, 4 blocks/CU = 32 waves).
//  - T5 setprio around MFMA clusters; tree max, trunc bf16 pack, defer-rescale
// ---------------------------------------------------------------------------
__global__ __launch_bounds__(512)
void flash_attn_mfma(const unsigned short* __restrict__ qg,
                     const unsigned short* __restrict__ kg,
                     const unsigned short* __restrict__ vt,
                     unsigned short* __restrict__ og) {
    __shared__ short Klds[2][64][64];   // 16 KB
    __shared__ short Vlds[2][64][64];   // 16 KB
    const int tid = threadIdx.x;
    const int lane = tid & 63;
    const int w = tid >> 6;             // 0..7
    const int g = lane >> 4, li = lane & 15;
    const int orig = blockIdx.x;                   // 0..511
    const int swz = (orig & 7) * 64 + (orig >> 3);
    const int bx = swz & 7;                        // q-tile pair index
    const int bh = swz >> 3;                       // head 0..63
    const size_t head = (size_t)bh * SEQ * HDIM;
    const int b = bh >> 4, h = bh & 15;

    const int c0r = tid >> 3, c0c = tid & 7;       // one 16B chunk per thread

    // permuted A-row for ak[m]: arow(m) = 32*(m>>1) + abase, abase = 8*(li>>2)+4*(m&1)+(li&3)
    const int abase0 = 8 * (li >> 2) + (li & 3);       // m even
    const int abase1 = abase0 + 4;                     // m odd

    for (int pass = 0; pass < 2; pass++) {
        const int qtile = pass ? (15 - bx) : bx;
        const int qbase = qtile * 128;
        const int qw = qbase + w * 16;             // 16 q-rows per wave
        const int nt = 2 * qtile + 2;

        // Q fragment: col q=li, k d=32*ds+8g+j
        short8 bq[2];
#pragma unroll
        for (int ds = 0; ds < 2; ds++)
            bq[ds] = *reinterpret_cast<const short8*>(
                &qg[head + (size_t)(qw + li) * HDIM + ds * 32 + g * 8]);

        f32x4 accO[4];
#pragma unroll
        for (int df = 0; df < 4; df++) accO[df] = (f32x4){0.f, 0.f, 0.f, 0.f};
        float mrow = -INFINITY;
        float lrow = 0.f;

        const unsigned short* kp = kg + head + (size_t)c0r * HDIM + c0c * 8;
        const unsigned short* vp = vt + head + (size_t)c0r * SEQ + c0c * 8;

        short8 kreg, vreg;
        kreg = *reinterpret_cast<const short8*>(kp);
        vreg = *reinterpret_cast<const short8*>(vp);
        kp += 64 * HDIM; vp += 64;
        {
            const int sw0 = (c0c ^ (c0r & 7)) * 8;
            *reinterpret_cast<short8*>(&Klds[0][c0r][sw0]) = kreg;
            *reinterpret_cast<short8*>(&Vlds[0][c0r][sw0]) = vreg;
        }
        __syncthreads();

        for (int t = 0; t < nt; t++) {
            const int kvbase = t * 64;
            const int buf = t & 1;
            const bool more = (t + 1 < nt);
            if (more) {      // issue next-tile loads NOW
                kreg = *reinterpret_cast<const short8*>(kp);
                vreg = *reinterpret_cast<const short8*>(vp);
                kp += 64 * HDIM; vp += 64;
            }

            if (kvbase <= qw + 15) {     // wave-uniform causal skip
                // ---- S^T = K·Q^T with permuted A rows ----
                // lane (g,li) gets s[m][r] = S[kv = 32*(m>>1)+8g+4*(m&1)+r][q=li]
                f32x4 s[4];
#pragma unroll
                for (int m = 0; m < 4; m++) s[m] = (f32x4){0.f, 0.f, 0.f, 0.f};
#pragma unroll
                for (int ds = 0; ds < 2; ds++) {
                    short8 ak[4];
#pragma unroll
                    for (int m = 0; m < 4; m++) {
                        int arow = 32 * (m >> 1) + ((m & 1) ? abase1 : abase0);
                        ak[m] = *reinterpret_cast<const short8*>(
                            &Klds[buf][arow][((ds * 4 + g) ^ (arow & 7)) * 8]);
                    }
                    __builtin_amdgcn_s_setprio(1);
#pragma unroll
                    for (int m = 0; m < 4; m++)
                        s[m] = __builtin_amdgcn_mfma_f32_16x16x32_bf16(
                            ak[m], bq[ds], s[m], 0, 0, 0);
                    __builtin_amdgcn_s_setprio(0);
                }
                // ---- mask (diag tiles only): kv = kvbase+32*(m>>1)+8g+4*(m&1)+r
                const bool diag = (kvbase + 63 > qw);
                if (diag) {
                    int q = qw + li;
#pragma unroll
                    for (int m = 0; m < 4; m++) {
                        int kv0 = kvbase + 32 * (m >> 1) + 8 * g + 4 * (m & 1);
#pragma unroll
                        for (int r = 0; r < 4; r++)
                            if (kv0 + r > q) s[m][r] = -INFINITY;
                    }
                }
                // ---- tile max (tree) + corr ----
                float a0 = fmaxf(fmaxf(s[0][0], s[0][1]), fmaxf(s[0][2], s[0][3]));
                float a1 = fmaxf(fmaxf(s[1][0], s[1][1]), fmaxf(s[1][2], s[1][3]));
                float a2 = fmaxf(fmaxf(s[2][0], s[2][1]), fmaxf(s[2][2], s[2][3]));
                float a3 = fmaxf(fmaxf(s[3][0], s[3][1]), fmaxf(s[3][2], s[3][3]));
                float tm = fmaxf(fmaxf(a0, a1), fmaxf(a2, a3));
                tm = fmaxf(tm, __shfl_xor(tm, 16));
                tm = fmaxf(tm, __shfl_xor(tm, 32));
                float mnew = fmaxf(mrow, tm);
                float corr = __builtin_amdgcn_exp2f(mrow - mnew);
                mrow = mnew;
                // ---- P = exp2(S-m); build PV B-operand IN REGISTERS ----
                float p[4][4];
                float sm[4];
#pragma unroll
                for (int m = 0; m < 4; m++) {
#pragma unroll
                    for (int r = 0; r < 4; r++)
                        p[m][r] = __builtin_amdgcn_exp2f(s[m][r] - mrow);
                    sm[m] = (p[m][0] + p[m][1]) + (p[m][2] + p[m][3]);
                }
                short8 bp[2];
#pragma unroll
                for (int ks = 0; ks < 2; ks++) {
                    unsigned u0 = (__float_as_uint(p[2 * ks][1]) & 0xFFFF0000u) |
                                  (__float_as_uint(p[2 * ks][0]) >> 16);
                    unsigned u1 = (__float_as_uint(p[2 * ks][3]) & 0xFFFF0000u) |
                                  (__float_as_uint(p[2 * ks][2]) >> 16);
                    unsigned u2 = (__float_as_uint(p[2 * ks + 1][1]) & 0xFFFF0000u) |
                                  (__float_as_uint(p[2 * ks + 1][0]) >> 16);
                    unsigned u3 = (__float_as_uint(p[2 * ks + 1][3]) & 0xFFFF0000u) |
                                  (__float_as_uint(p[2 * ks + 1][2]) >> 16);
                    unsigned q4[4] = {u0, u1, u2, u3};
                    bp[ks] = *reinterpret_cast<short8*>(q4);
                }
                float ts = (sm[0] + sm[1]) + (sm[2] + sm[3]);
                ts += __shfl_xor(ts, 16);
                ts += __shfl_xor(ts, 32);
                lrow = lrow * corr + ts;
                // ---- O rescale (skipped when max unchanged across wave) ----
                if (!__all((int)(corr == 1.0f))) {
#pragma unroll
                    for (int df = 0; df < 4; df++) {
                        accO[df][0] *= corr; accO[df][1] *= corr;
                        accO[df][2] *= corr; accO[df][3] *= corr;
                    }
                }
                // ---- O^T += V^T·P^T :  D[d=16df+4g+r][q=li] ----
#pragma unroll
                for (int ks = 0; ks < 2; ks++) {
                    short8 av[4];
#pragma unroll
                    for (int df = 0; df < 4; df++) {
                        int vrow = li + 16 * df;
                        av[df] = *reinterpret_cast<const short8*>(
                            &Vlds[buf][vrow][((ks * 4 + g) ^ (vrow & 7)) * 8]);
                    }
                    __builtin_amdgcn_s_setprio(1);
#pragma unroll
                    for (int df = 0; df < 4; df++)
                        accO[df] = __builtin_amdgcn_mfma_f32_16x16x32_bf16(
                            av[df], bp[ks], accO[df], 0, 0, 0);
                    __builtin_amdgcn_s_setprio(0);
                }
            }

            if (more) {
                const int nbuf = buf ^ 1;
                const int sw0 = (c0c ^ (c0r & 7)) * 8;
                *reinterpret_cast<short8*>(&Klds[nbuf][c0r][sw0]) = kreg;
                *reinterpret_cast<short8*>(&Vlds[nbuf][c0r][sw0]) = vreg;
            }
            __syncthreads();
        }

        // epilogue: O[q][d] = accO^T / l
        {
            float inv = 1.0f / lrow;
            int q = qw + li;
            size_t rowoff = (size_t)(b * SEQ + q) * DIMC + h * HDIM;
#pragma unroll
            for (int df = 0; df < 4; df++) {
                short4v pk;
#pragma unroll
                for (int r = 0; r < 4; r++) pk[r] = f2bf(accO[df][r] * inv);
                *reinterpret_cast<short4v*>(&og[rowoff + 16 * df + 4 * g]) = pk;
            }
        }
        __syncthreads();   // protect LDS before next pass's prologue writes
    }
}

extern "C" void kernel_launch(void* const* d_in, const int* in_sizes, int n_in,
                              void* d_out, int out_size, void* d_ws, size_t ws_size,
                              hipStream_t stream) {
    const float* x      = (const float*)d_in[0];   // [4,2048,1024]
    const float* w_qkv  = (const float*)d_in[1];   // [1024,3072]
    const float* w_proj = (const float*)d_in[2];   // [1024,1024]
    const float* b_proj = (const float*)d_in[3];   // [1024]
    float* out = (float*)d_out;                    // [4,2048,1024] fp32

    char* w = (char*)d_ws;
    unsigned short* qb  = (unsigned short*)(w);                        // 16 MB
    unsigned short* kb  = (unsigned short*)(w + ((size_t)16 << 20));   // 16 MB
    unsigned short* vtb = (unsigned short*)(w + ((size_t)32 << 20));   // 16 MB [B,H,D,S]
    unsigned short* ao  = (unsigned short*)(w + ((size_t)48 << 20));   // 16 MB
    unsigned short* wqt = (unsigned short*)(w + ((size_t)64 << 20));   // 6 MB
    unsigned short* wpt = (unsigned short*)(w + ((size_t)72 << 20));   // 2 MB
    unsigned short* xbf = (unsigned short*)(w + ((size_t)80 << 20));   // 16 MB

    xcvt<<<NROWS * DIMC / (256 * 8), 256, 0, stream>>>(x, xbf);
    transpose_cvt<<<dim3(3 * DIMC / 64, DIMC / 64), 256, 0, stream>>>(w_qkv, wqt, 3 * DIMC);
    transpose_cvt<<<dim3(DIMC / 64, DIMC / 64), 256, 0, stream>>>(w_proj, wpt, DIMC);
    qkv_gemm_mfma<<<dim3(3 * DIMC / 128, NROWS / 128), 256, 0, stream>>>(xbf, wqt, qb, kb, vtb);
    flash_attn_mfma<<<512, 512, 0, stream>>>(qb, kb, vtb, ao);
    proj_gemm_mfma<<<dim3(DIMC / 128, NROWS / 128), 256, 0, stream>>>(ao, wpt, b_proj, out);
}